// Round 3
// baseline (111797.998 us; speedup 1.0000x reference)
//
#include <hip/hip_runtime.h>

typedef unsigned short u16;
typedef unsigned int   u32;
typedef __bf16 bf16x8 __attribute__((ext_vector_type(8)));
typedef float  f32x4  __attribute__((ext_vector_type(4)));

#define T_SEQ 65536

__device__ __forceinline__ float bf2f(u16 v){ return __uint_as_float(((u32)v) << 16); }
__device__ __forceinline__ float bflo(u32 w){ return __uint_as_float(w << 16); }
__device__ __forceinline__ float bfhi(u32 w){ return __uint_as_float(w & 0xFFFF0000u); }
__device__ __forceinline__ u16 f2bf(float f){
  u32 u = __float_as_uint(f);
  u32 r = (u + 0x7FFFu + ((u >> 16) & 1u)) >> 16;
  return (u16)r;
}
__device__ __forceinline__ float sigm(float x){ return 1.0f / (1.0f + __expf(-x)); }
__device__ __forceinline__ float tanh_(float x){ return 1.0f - 2.0f / (1.0f + __expf(2.0f * x)); }

// dtype-flagged boundary access: f==1 -> float32, f==0 -> bf16
__device__ __forceinline__ float ldf(const void* p, size_t i, int f){
  return f ? ((const float*)p)[i] : bf2f(((const u16*)p)[i]);
}
__device__ __forceinline__ void stf(void* p, size_t i, float v, int f){
  if (f) ((float*)p)[i] = v; else ((u16*)p)[i] = f2bf(v);
}

__device__ __forceinline__ bf16x8 ldg_frag(const u16* p){
  uint4 v = *(const uint4*)p;
  return __builtin_bit_cast(bf16x8, v);
}
__device__ __forceinline__ bf16x8 load_frag_dyn(const void* p, int off, int f){
  if (!f) return ldg_frag((const u16*)p + off);
  union { u16 h[8]; bf16x8 v; } t;
  const float* q = (const float*)p + off;
#pragma unroll
  for (int j = 0; j < 8; ++j) t.h[j] = f2bf(q[j]);
  return t.v;
}

// ---------------- K0: per-array dtype detector ----------------
// bf16-packed data: every u16 half is a bf16 of ~N(0,1)/U data -> exponent in [96,135].
// f32 data: low u16 halves are random mantissa bits -> ~84% outside that band.
// all-zero arrays give bad==good==0 -> default bf16 (value-correct for zeros).
struct Ptrs { const void* p[15]; int n[15]; };

__global__ void k_detect(Ptrs ptrs, int* flags){
  const int i = threadIdx.x;
  if (i >= 15) return;
  const u32* w = (const u32*)ptrs.p[i];
  int words = ptrs.n[i] >> 1; if (words > 256) words = 256;
  int bad = 0, good = 0;
  for (int j = 0; j < words; ++j){
    u32 lo = w[j] & 0xFFFFu;
    if (lo == 0) continue;
    u32 e = (lo >> 7) & 0xFFu;
    if (e >= 96 && e <= 135) ++good; else ++bad;
  }
  flags[i] = (bad > good) ? 1 : 0;
}

// ---------------- K1: preA[t][r] = x[t] @ WA1^T + bA1 + bA2  (bf16 internal out) ----------------
__global__ __launch_bounds__(512) void k_pre(const void* __restrict__ x, const void* __restrict__ WA1,
                                             const void* __restrict__ bA1, const void* __restrict__ bA2,
                                             const int* __restrict__ flags,
                                             u16* __restrict__ preA, int t0){
  __shared__ __align__(16) float sx[32 * 128];
  const int fx = flags[0], fw = flags[5], f1 = flags[6], f2 = flags[8];
  const int tid = threadIdx.x;
  const int tl0 = blockIdx.x * 32;
  const int tg0 = t0 + tl0;
  for (int i = tid; i < 32 * 128; i += 512) sx[i] = ldf(x, (size_t)tg0 * 128 + i, fx);
  __syncthreads();
  const int r = tid; // 0..511
  float bias = ldf(bA1, r, f1) + ldf(bA2, r, f2);
  float acc[32];
#pragma unroll
  for (int t = 0; t < 32; ++t) acc[t] = bias;
  if (!fw){
    const u32* wrow = (const u32*)WA1 + r * 64;
    for (int c = 0; c < 32; ++c){
      uint2 wp = *(const uint2*)(wrow + 2 * c);
      float w0 = bflo(wp.x), w1 = bfhi(wp.x), w2 = bflo(wp.y), w3 = bfhi(wp.y);
#pragma unroll
      for (int t = 0; t < 32; ++t){
        const f32x4 xv = *(const f32x4*)&sx[t * 128 + 4 * c];
        acc[t] += w0 * xv.x + w1 * xv.y + w2 * xv.z + w3 * xv.w;
      }
    }
  } else {
    const float* wrow = (const float*)WA1 + r * 128;
    for (int c = 0; c < 32; ++c){
      const f32x4 wv = *(const f32x4*)(wrow + 4 * c);
#pragma unroll
      for (int t = 0; t < 32; ++t){
        const f32x4 xv = *(const f32x4*)&sx[t * 128 + 4 * c];
        acc[t] += wv.x * xv.x + wv.y * xv.y + wv.z * xv.z + wv.w * xv.w;
      }
    }
  }
  for (int t = 0; t < 32; ++t) preA[(size_t)(tl0 + t) * 512 + r] = f2bf(acc[t]);
}

// ---------------- K2: sequential 2-layer LSTM over one chunk, single workgroup ----------------
__global__ __launch_bounds__(512, 2) void k_lstm(
    const u16* __restrict__ preA,                // chunk-local [L][512] bf16 (internal)
    const void* __restrict__ hA0, const void* __restrict__ cA0,
    const void* __restrict__ hB0, const void* __restrict__ cB0,
    const void* __restrict__ WA2, const void* __restrict__ WB1, const void* __restrict__ WB2,
    const void* __restrict__ bB1, const void* __restrict__ bB2,
    const int* __restrict__ flags,
    float* __restrict__ stF,                     // ws state: cA[128], cB[128] f32
    u16*   __restrict__ stH,                     // ws state: hA[128], hB[128] bf16
    u16*   __restrict__ hb,                      // chunk-local [L][128] bf16 (internal)
    void*  __restrict__ outBase,                 // d_out; states at element offset T_SEQ*128
    int t0, int L)
{
  __shared__ __align__(16) u16   sPre[2][16 * 512]; // 32 KB double-buffered preA chunks
  __shared__ __align__(16) u16   sHb[16 * 128];     // 4 KB hB buffer, flushed every 16 steps
  __shared__ __align__(16) float sGates[512];
  __shared__ __align__(16) u16   sHa[128];
  __shared__ __align__(16) u16   sHbb[128];

  const int tid = threadIdx.x;
  const int w = tid >> 6;
  const int l = tid & 63;
  const int q = l >> 4;
  const int m = l & 15;
  const bool first = (t0 == 0);
  const bool last  = (t0 + L == T_SEQ);
  const int fWA2 = flags[7], fWB1 = flags[9], fWB2 = flags[11];
  const int fb1 = flags[10], fb2 = flags[12];
  const int fst = flags[1]; // states dtype (zeros -> either is value-correct)
  const int fo  = flags[0]; // output dtype keyed to x

  // Persistent weight fragments: wave w owns rows w*64..w*64+63 (4 row-tiles of 16)
  // A-frag layout (mfma_f32_16x16x32_bf16): A[m=lane&15][k=(lane>>4)*8+j]
  bf16x8 wA[4][4], w1f[4][4], w2f[4][4];
#pragma unroll
  for (int rt = 0; rt < 4; ++rt){
    const int row = (w * 4 + rt) * 16 + m;
#pragma unroll
    for (int kt = 0; kt < 4; ++kt){
      const int off = row * 128 + kt * 32 + q * 8;
      wA[rt][kt]  = load_frag_dyn(WA2, off, fWA2);
      w1f[rt][kt] = load_frag_dyn(WB1, off, fWB1);
      w2f[rt][kt] = load_frag_dyn(WB2, off, fWB2);
    }
  }

  float cA = 0.f, cB = 0.f;
  float bb[4] = {0.f, 0.f, 0.f, 0.f};
  if (tid < 128){
    if (first){
      cA = ldf(cA0, tid, fst); cB = ldf(cB0, tid, fst);
      sHa[tid]  = f2bf(ldf(hA0, tid, fst));
      sHbb[tid] = f2bf(ldf(hB0, tid, fst));
    } else {
      cA = stF[tid]; cB = stF[128 + tid];
      sHa[tid]  = stH[tid];
      sHbb[tid] = stH[128 + tid];
    }
#pragma unroll
    for (int g = 0; g < 4; ++g) bb[g] = ldf(bB1, g * 128 + tid, fb1) + ldf(bB2, g * 128 + tid, fb2);
  }
  // stage chunk 0 (16 KB = 1024 uint4)
  {
    const uint4* src = (const uint4*)preA;
    uint4* dst = (uint4*)&sPre[0][0];
    dst[tid]       = src[tid];
    dst[tid + 512] = src[tid + 512];
  }
  __syncthreads();

  for (int t = 0; t < L; ++t){
    const int slot = t & 15;
    const int buf  = (t >> 4) & 1;

    // ---- Phase A: gates_A = WA2 @ hA[t-1] ----
    f32x4 acc[4];
#pragma unroll
    for (int rt = 0; rt < 4; ++rt) acc[rt] = (f32x4){0.f, 0.f, 0.f, 0.f};
#pragma unroll
    for (int kt = 0; kt < 4; ++kt){
      bf16x8 bh = __builtin_bit_cast(bf16x8, *(const uint4*)&sHa[kt * 32 + q * 8]);
#pragma unroll
      for (int rt = 0; rt < 4; ++rt)
        acc[rt] = __builtin_amdgcn_mfma_f32_16x16x32_bf16(wA[rt][kt], bh, acc[rt], 0, 0, 0);
    }
    if (m == 0){ // C/D col 0: lane 16q holds rows q*4+reg
#pragma unroll
      for (int rt = 0; rt < 4; ++rt)
        *(f32x4*)&sGates[(w * 4 + rt) * 16 + q * 4] = acc[rt];
    }
    __syncthreads();

    // ---- cell A (waves 0-1) | hb flush + next-chunk staging (waves 2-7) ----
    if (tid < 128){
      const u16* pc = &sPre[buf][slot * 512];
      float gi = sigm (bf2f(pc[tid])        + sGates[tid]);
      float gf = sigm (bf2f(pc[128 + tid])  + sGates[128 + tid]);
      float gg = tanh_(bf2f(pc[256 + tid])  + sGates[256 + tid]);
      float go = sigm (bf2f(pc[384 + tid])  + sGates[384 + tid]);
      cA = gf * cA + gi * gg;
      float ha = go * tanh_(cA);
      sHa[tid] = f2bf(ha);
    } else if (slot == 0){
      if (t > 0){
        const int base32 = (t - 16) * 64;
        const u32* src = (const u32*)sHb;
        u32* dst = (u32*)hb;
        for (int i = tid - 128; i < 1024; i += 384) dst[base32 + i] = src[i];
      }
      const int nc = (t >> 4) + 1;
      if (nc < L / 16){
        const uint4* src = (const uint4*)(preA + (size_t)nc * 16 * 512);
        uint4* dst = (uint4*)&sPre[nc & 1][0];
        for (int i = tid - 128; i < 1024; i += 384) dst[i] = src[i];
      }
    }
    __syncthreads();

    // ---- Phase B: gates_B = WB1 @ hA[t] + WB2 @ hB[t-1] ----
    f32x4 bacc[4];
#pragma unroll
    for (int rt = 0; rt < 4; ++rt) bacc[rt] = (f32x4){0.f, 0.f, 0.f, 0.f};
#pragma unroll
    for (int kt = 0; kt < 4; ++kt){
      bf16x8 ba  = __builtin_bit_cast(bf16x8, *(const uint4*)&sHa[kt * 32 + q * 8]);
      bf16x8 bbv = __builtin_bit_cast(bf16x8, *(const uint4*)&sHbb[kt * 32 + q * 8]);
#pragma unroll
      for (int rt = 0; rt < 4; ++rt){
        bacc[rt] = __builtin_amdgcn_mfma_f32_16x16x32_bf16(w1f[rt][kt], ba,  bacc[rt], 0, 0, 0);
        bacc[rt] = __builtin_amdgcn_mfma_f32_16x16x32_bf16(w2f[rt][kt], bbv, bacc[rt], 0, 0, 0);
      }
    }
    if (m == 0){
#pragma unroll
      for (int rt = 0; rt < 4; ++rt)
        *(f32x4*)&sGates[(w * 4 + rt) * 16 + q * 4] = bacc[rt];
    }
    __syncthreads();

    // ---- cell B ----
    if (tid < 128){
      float gi = sigm (bb[0] + sGates[tid]);
      float gf = sigm (bb[1] + sGates[128 + tid]);
      float gg = tanh_(bb[2] + sGates[256 + tid]);
      float go = sigm (bb[3] + sGates[384 + tid]);
      cB = gf * cB + gi * gg;
      float hb_v = go * tanh_(cB);
      u16 hbq = f2bf(hb_v);
      sHbb[tid] = hbq;
      sHb[slot * 128 + tid] = hbq;
    }
    __syncthreads();
  }

  // epilogue: flush last 16 hB rows + persist state
  {
    const int base32 = (L - 16) * 64;
    const u32* src = (const u32*)sHb;
    u32* dst = (u32*)hb;
    for (int i = tid; i < 1024; i += 512) dst[base32 + i] = src[i];
  }
  if (tid < 128){
    stF[tid] = cA; stF[128 + tid] = cB;
    stH[tid] = sHa[tid]; stH[128 + tid] = sHbb[tid];
    if (last){
      const size_t ob = (size_t)T_SEQ * 128;
      stf(outBase, ob + tid,        bf2f(sHa[tid]), fo);
      stf(outBase, ob + 128 + tid,  cA,             fo);
      stf(outBase, ob + 256 + tid,  bf2f(sHbb[tid]),fo);
      stf(outBase, ob + 384 + tid,  cB,             fo);
    }
  }
}

// ---------------- K3: logits[t][v] = hb[t] @ Wfc^T + bfc ----------------
__global__ __launch_bounds__(256) void k_fc(const u16* __restrict__ hb,
                                            const void* __restrict__ Wfc, const void* __restrict__ bfc,
                                            const int* __restrict__ flags,
                                            void* __restrict__ out, int t0){
  __shared__ __align__(16) float sh[32 * 128];
  const int fw = flags[13], fb = flags[14], fo = flags[0];
  const int tid = threadIdx.x;
  const int tl0 = blockIdx.x * 32;
  for (int i = tid; i < 32 * 128; i += 256) sh[i] = bf2f(hb[(size_t)tl0 * 128 + i]);
  __syncthreads();
  const int v  = tid & 127;
  const int tt = tid >> 7; // 0..1
  float bias = ldf(bfc, v, fb);
  float acc[16];
#pragma unroll
  for (int j = 0; j < 16; ++j) acc[j] = bias;
  if (!fw){
    const u32* wrow = (const u32*)Wfc + v * 64;
    for (int c = 0; c < 32; ++c){
      uint2 wp = *(const uint2*)(wrow + 2 * c);
      float w0 = bflo(wp.x), w1 = bfhi(wp.x), w2 = bflo(wp.y), w3 = bfhi(wp.y);
#pragma unroll
      for (int j = 0; j < 16; ++j){
        const f32x4 xv = *(const f32x4*)&sh[(tt + 2 * j) * 128 + 4 * c];
        acc[j] += w0 * xv.x + w1 * xv.y + w2 * xv.z + w3 * xv.w;
      }
    }
  } else {
    const float* wrow = (const float*)Wfc + v * 128;
    for (int c = 0; c < 32; ++c){
      const f32x4 wv = *(const f32x4*)(wrow + 4 * c);
#pragma unroll
      for (int j = 0; j < 16; ++j){
        const f32x4 xv = *(const f32x4*)&sh[(tt + 2 * j) * 128 + 4 * c];
        acc[j] += wv.x * xv.x + wv.y * xv.y + wv.z * xv.z + wv.w * xv.w;
      }
    }
  }
  for (int j = 0; j < 16; ++j)
    stf(out, (size_t)(t0 + tl0 + tt + 2 * j) * 128 + v, acc[j], fo);
}

extern "C" void kernel_launch(void* const* d_in, const int* in_sizes, int n_in,
                              void* d_out, int out_size, void* d_ws, size_t ws_size,
                              hipStream_t stream) {
  // ---- ws layout ----
  // [0,1024)      stF (cA,cB f32)
  // [1024,1536)   stH (hA,hB bf16)
  // [1536,1600)   flags (int[16])
  // [4096, +CHUNK*1024)           preA bf16 [CHUNK][512]
  // [4096+CHUNK*1024, +CHUNK*256) hb   bf16 [CHUNK][128]
  int CHUNK = 32;
  for (int c = T_SEQ; c >= 32; c >>= 1){
    size_t need = 4096 + (size_t)c * 1024 + (size_t)c * 256;
    if (need <= ws_size){ CHUNK = c; break; }
  }
  float* stF   = (float*)d_ws;
  u16*   stH   = (u16*)((char*)d_ws + 1024);
  int*   flags = (int*)((char*)d_ws + 1536);
  u16*   preA  = (u16*)((char*)d_ws + 4096);
  u16*   hb    = (u16*)((char*)d_ws + 4096 + (size_t)CHUNK * 1024);

  Ptrs ptrs;
  for (int i = 0; i < 15; ++i){ ptrs.p[i] = d_in[i]; ptrs.n[i] = in_sizes[i]; }
  k_detect<<<1, 64, 0, stream>>>(ptrs, flags);

  const int nChunks = T_SEQ / CHUNK;
  for (int c = 0; c < nChunks; ++c){
    const int t0 = c * CHUNK;
    k_pre <<<CHUNK / 32, 512, 0, stream>>>(d_in[0], d_in[5], d_in[6], d_in[8], flags, preA, t0);
    k_lstm<<<1,          512, 0, stream>>>(preA, d_in[1], d_in[2], d_in[3], d_in[4],
                                           d_in[7], d_in[9], d_in[11], d_in[10], d_in[12],
                                           flags, stF, stH, hb, d_out, t0, CHUNK);
    k_fc  <<<CHUNK / 32, 256, 0, stream>>>(hb, d_in[13], d_in[14], flags, d_out, t0);
  }
}

// Round 4
// 102449.451 us; speedup vs baseline: 1.0913x; 1.0913x over previous
//
#include <hip/hip_runtime.h>

typedef unsigned short u16;
typedef unsigned int   u32;
typedef __bf16 bf16x8 __attribute__((ext_vector_type(8)));
typedef float  f32x4  __attribute__((ext_vector_type(4)));

#define T_SEQ 65536

__device__ __forceinline__ float bf2f(u16 v){ return __uint_as_float(((u32)v) << 16); }
__device__ __forceinline__ float bflo(u32 w){ return __uint_as_float(w << 16); }
__device__ __forceinline__ float bfhi(u32 w){ return __uint_as_float(w & 0xFFFF0000u); }
__device__ __forceinline__ u16 f2bf(float f){
  u32 u = __float_as_uint(f);
  u32 r = (u + 0x7FFFu + ((u >> 16) & 1u)) >> 16;
  return (u16)r;
}
__device__ __forceinline__ float sigm(float x){ return 1.0f / (1.0f + __expf(-x)); }
__device__ __forceinline__ float tanh_(float x){ return 1.0f - 2.0f / (1.0f + __expf(2.0f * x)); }

// dtype-flagged boundary access: f==1 -> float32, f==0 -> bf16
__device__ __forceinline__ float ldf(const void* p, size_t i, int f){
  return f ? ((const float*)p)[i] : bf2f(((const u16*)p)[i]);
}
__device__ __forceinline__ void stf(void* p, size_t i, float v, int f){
  if (f) ((float*)p)[i] = v; else ((u16*)p)[i] = f2bf(v);
}

__device__ __forceinline__ bf16x8 ldg_frag(const u16* p){
  uint4 v = *(const uint4*)p;
  return __builtin_bit_cast(bf16x8, v);
}
__device__ __forceinline__ bf16x8 load_frag_dyn(const void* p, int off, int f){
  if (!f) return ldg_frag((const u16*)p + off);
  union { u16 h[8]; bf16x8 v; } t;
  const float* q = (const float*)p + off;
#pragma unroll
  for (int j = 0; j < 8; ++j) t.h[j] = f2bf(q[j]);
  return t.v;
}
__device__ __forceinline__ bf16x8 lds_frag(const u16* p){
  uint4 v = *(const uint4*)p;
  return __builtin_bit_cast(bf16x8, v);
}

// ---------------- K0: per-array dtype detector ----------------
struct Ptrs { const void* p[15]; int n[15]; };

__global__ void k_detect(Ptrs ptrs, int* flags){
  const int i = threadIdx.x;
  if (i >= 15) return;
  const u32* w = (const u32*)ptrs.p[i];
  int words = ptrs.n[i] >> 1; if (words > 256) words = 256;
  int bad = 0, good = 0;
  for (int j = 0; j < words; ++j){
    u32 lo = w[j] & 0xFFFFu;
    if (lo == 0) continue;
    u32 e = (lo >> 7) & 0xFFu;
    if (e >= 96 && e <= 135) ++good; else ++bad;
  }
  flags[i] = (bad > good) ? 1 : 0;
}

// ---------------- K1: preA[t][r] = x[t] @ WA1^T + bA1 + bA2  (bf16 internal out) ----------------
__global__ __launch_bounds__(512) void k_pre(const void* __restrict__ x, const void* __restrict__ WA1,
                                             const void* __restrict__ bA1, const void* __restrict__ bA2,
                                             const int* __restrict__ flags,
                                             u16* __restrict__ preA, int t0){
  __shared__ __align__(16) float sx[32 * 128];
  const int fx = flags[0], fw = flags[5], f1 = flags[6], f2 = flags[8];
  const int tid = threadIdx.x;
  const int tl0 = blockIdx.x * 32;
  const int tg0 = t0 + tl0;
  for (int i = tid; i < 32 * 128; i += 512) sx[i] = ldf(x, (size_t)tg0 * 128 + i, fx);
  __syncthreads();
  const int r = tid; // 0..511
  float bias = ldf(bA1, r, f1) + ldf(bA2, r, f2);
  float acc[32];
#pragma unroll
  for (int t = 0; t < 32; ++t) acc[t] = bias;
  if (!fw){
    const u32* wrow = (const u32*)WA1 + r * 64;
    for (int c = 0; c < 32; ++c){
      uint2 wp = *(const uint2*)(wrow + 2 * c);
      float w0 = bflo(wp.x), w1 = bfhi(wp.x), w2 = bflo(wp.y), w3 = bfhi(wp.y);
#pragma unroll
      for (int t = 0; t < 32; ++t){
        const f32x4 xv = *(const f32x4*)&sx[t * 128 + 4 * c];
        acc[t] += w0 * xv.x + w1 * xv.y + w2 * xv.z + w3 * xv.w;
      }
    }
  } else {
    const float* wrow = (const float*)WA1 + r * 128;
    for (int c = 0; c < 32; ++c){
      const f32x4 wv = *(const f32x4*)(wrow + 4 * c);
#pragma unroll
      for (int t = 0; t < 32; ++t){
        const f32x4 xv = *(const f32x4*)&sx[t * 128 + 4 * c];
        acc[t] += wv.x * xv.x + wv.y * xv.y + wv.z * xv.z + wv.w * xv.w;
      }
    }
  }
  for (int t = 0; t < 32; ++t) preA[(size_t)(tl0 + t) * 512 + r] = f2bf(acc[t]);
}

// ---------------- K2: sequential 2-layer LSTM, fused 2-barrier step ----------------
// Per fused iteration t (entry: sHa=hA(t), sHbb=hB(t-1), cA reg=cA(t) [tid128-255], cB reg=cB(t-1) [tid<128]):
//   MFMA phase: gB(t)=WB1@hA(t)+WB2@hB(t-1) AND gA(t+1)=WA2@hA(t); staging/flush at slot==0
//   barrier
//   cell phase: tid<128 -> cellB(t); tid128-255 -> cellA(t+1)  (skipped at t==L-1)
//   barrier
__global__ __launch_bounds__(512, 2) void k_lstm(
    const u16* __restrict__ preA,
    const void* __restrict__ hA0, const void* __restrict__ cA0,
    const void* __restrict__ hB0, const void* __restrict__ cB0,
    const void* __restrict__ WA2, const void* __restrict__ WB1, const void* __restrict__ WB2,
    const void* __restrict__ bB1, const void* __restrict__ bB2,
    const int* __restrict__ flags,
    float* __restrict__ stF, u16* __restrict__ stH,
    u16* __restrict__ hb, void* __restrict__ outBase,
    int t0, int L)
{
  __shared__ __align__(16) u16   sPre[2][16 * 512]; // 32 KB double-buffered preA chunks
  __shared__ __align__(16) u16   sHb[16 * 128];     // 4 KB hB buffer
  __shared__ __align__(16) float sGA[512];          // gates A(t+1)
  __shared__ __align__(16) float sGB[512];          // gates B(t)
  __shared__ __align__(16) u16   sHa[128];
  __shared__ __align__(16) u16   sHbb[128];

  const int tid = threadIdx.x;
  const int w = tid >> 6;
  const int l = tid & 63;
  const int q = l >> 4;
  const int m = l & 15;
  const bool first = (t0 == 0);
  const bool last  = (t0 + L == T_SEQ);
  const int fWA2 = flags[7], fWB1 = flags[9], fWB2 = flags[11];
  const int fb1 = flags[10], fb2 = flags[12];
  const int fst = flags[1];
  const int fo  = flags[0];

  // Persistent weight fragments: wave w owns rows w*64..w*64+63 (4 row-tiles of 16)
  bf16x8 wA[4][4], w1f[4][4], w2f[4][4];
#pragma unroll
  for (int rt = 0; rt < 4; ++rt){
    const int row = (w * 4 + rt) * 16 + m;
#pragma unroll
    for (int kt = 0; kt < 4; ++kt){
      const int off = row * 128 + kt * 32 + q * 8;
      wA[rt][kt]  = load_frag_dyn(WA2, off, fWA2);
      w1f[rt][kt] = load_frag_dyn(WB1, off, fWB1);
      w2f[rt][kt] = load_frag_dyn(WB2, off, fWB2);
    }
  }

  float cA = 0.f, cB = 0.f;
  float bb[4] = {0.f, 0.f, 0.f, 0.f};
  if (tid < 128){
    if (first){
      cB = ldf(cB0, tid, fst);
      sHa[tid]  = f2bf(ldf(hA0, tid, fst));
      sHbb[tid] = f2bf(ldf(hB0, tid, fst));
    } else {
      cB = stF[128 + tid];
      sHa[tid]  = stH[tid];
      sHbb[tid] = stH[128 + tid];
    }
#pragma unroll
    for (int g = 0; g < 4; ++g) bb[g] = ldf(bB1, g * 128 + tid, fb1) + ldf(bB2, g * 128 + tid, fb2);
  } else if (tid < 256){
    const int d = tid - 128;
    cA = first ? ldf(cA0, d, fst) : stF[d];
  }
  // stage chunk 0 (16 KB = 1024 uint4)
  {
    const uint4* src = (const uint4*)preA;
    uint4* dst = (uint4*)&sPre[0][0];
    dst[tid]       = src[tid];
    dst[tid + 512] = src[tid + 512];
  }
  __syncthreads();

  // ---- prologue: gA(t0) = WA2 @ hA(t0-1); cellA(t0) -> sHa = hA(t0) ----
  {
    f32x4 acc[4];
#pragma unroll
    for (int rt = 0; rt < 4; ++rt) acc[rt] = (f32x4){0.f, 0.f, 0.f, 0.f};
#pragma unroll
    for (int kt = 0; kt < 4; ++kt){
      bf16x8 bh = lds_frag(&sHa[kt * 32 + q * 8]);
#pragma unroll
      for (int rt = 0; rt < 4; ++rt)
        acc[rt] = __builtin_amdgcn_mfma_f32_16x16x32_bf16(wA[rt][kt], bh, acc[rt], 0, 0, 0);
    }
    if (m == 0){
#pragma unroll
      for (int rt = 0; rt < 4; ++rt)
        *(f32x4*)&sGA[(w * 4 + rt) * 16 + q * 4] = acc[rt];
    }
    __syncthreads();
    if (tid >= 128 && tid < 256){
      const int d = tid - 128;
      const u16* pc = &sPre[0][0];
      float gi = sigm (bf2f(pc[d])        + sGA[d]);
      float gf = sigm (bf2f(pc[128 + d])  + sGA[128 + d]);
      float gg = tanh_(bf2f(pc[256 + d])  + sGA[256 + d]);
      float go = sigm (bf2f(pc[384 + d])  + sGA[384 + d]);
      cA = gf * cA + gi * gg;
      sHa[d] = f2bf(go * tanh_(cA));
    }
    __syncthreads();
  }

  for (int t = 0; t < L; ++t){
    const int slot = t & 15;

    // ---- MFMA phase ----
    uint4 st0, st1;
    bool doStage = false;
    int nc = 0;
    if (slot == 0){
      nc = (t >> 4) + 1;
      if (nc < (L >> 4)){
        doStage = true;
        const uint4* src = (const uint4*)preA;
        st0 = src[(size_t)nc * 1024 + tid];
        st1 = src[(size_t)nc * 1024 + 512 + tid];
      }
      if (t > 0 && tid < 256){ // flush previous 16 hB rows
        const uint4* s = (const uint4*)sHb;
        ((uint4*)hb)[(size_t)(t - 16) * 16 + tid] = s[tid];
      }
    }

    f32x4 ga[4], gb[4];
#pragma unroll
    for (int rt = 0; rt < 4; ++rt){ ga[rt] = (f32x4){0.f,0.f,0.f,0.f}; gb[rt] = (f32x4){0.f,0.f,0.f,0.f}; }
#pragma unroll
    for (int kt = 0; kt < 4; ++kt){
      bf16x8 bhA = lds_frag(&sHa [kt * 32 + q * 8]);
      bf16x8 bhB = lds_frag(&sHbb[kt * 32 + q * 8]);
#pragma unroll
      for (int rt = 0; rt < 4; ++rt){
        ga[rt] = __builtin_amdgcn_mfma_f32_16x16x32_bf16(wA[rt][kt],  bhA, ga[rt], 0, 0, 0);
        gb[rt] = __builtin_amdgcn_mfma_f32_16x16x32_bf16(w1f[rt][kt], bhA, gb[rt], 0, 0, 0);
        gb[rt] = __builtin_amdgcn_mfma_f32_16x16x32_bf16(w2f[rt][kt], bhB, gb[rt], 0, 0, 0);
      }
    }
    if (m == 0){
#pragma unroll
      for (int rt = 0; rt < 4; ++rt){
        *(f32x4*)&sGA[(w * 4 + rt) * 16 + q * 4] = ga[rt];
        *(f32x4*)&sGB[(w * 4 + rt) * 16 + q * 4] = gb[rt];
      }
    }
    if (doStage){
      uint4* dst = (uint4*)&sPre[nc & 1][0];
      dst[tid]       = st0;
      dst[tid + 512] = st1;
    }
    __syncthreads();

    // ---- cell phase: cellB(t) on tid<128 || cellA(t+1) on tid 128-255 ----
    if (tid < 128){
      float gi = sigm (bb[0] + sGB[tid]);
      float gf = sigm (bb[1] + sGB[128 + tid]);
      float gg = tanh_(bb[2] + sGB[256 + tid]);
      float go = sigm (bb[3] + sGB[384 + tid]);
      cB = gf * cB + gi * gg;
      u16 hq = f2bf(go * tanh_(cB));
      sHbb[tid] = hq;
      sHb[slot * 128 + tid] = hq;
    } else if (tid < 256 && t < L - 1){
      const int d = tid - 128;
      const int s1 = (t + 1) & 15;
      const int b1 = ((t + 1) >> 4) & 1;
      const u16* pc = &sPre[b1][s1 * 512];
      float gi = sigm (bf2f(pc[d])        + sGA[d]);
      float gf = sigm (bf2f(pc[128 + d])  + sGA[128 + d]);
      float gg = tanh_(bf2f(pc[256 + d])  + sGA[256 + d]);
      float go = sigm (bf2f(pc[384 + d])  + sGA[384 + d]);
      cA = gf * cA + gi * gg;
      sHa[d] = f2bf(go * tanh_(cA));
    }
    __syncthreads();
  }

  // epilogue: flush last 16 hB rows + persist state
  if (tid < 256){
    const uint4* s = (const uint4*)sHb;
    ((uint4*)hb)[(size_t)(L - 16) * 16 + tid] = s[tid];
  }
  if (tid < 128){
    stF[128 + tid] = cB;
    stH[tid] = sHa[tid]; stH[128 + tid] = sHbb[tid];
    if (last){
      const size_t ob = (size_t)T_SEQ * 128;
      stf(outBase, ob + tid,        bf2f(sHa[tid]),  fo);
      stf(outBase, ob + 256 + tid,  bf2f(sHbb[tid]), fo);
      stf(outBase, ob + 384 + tid,  cB,              fo);
    }
  } else if (tid < 256){
    const int d = tid - 128;
    stF[d] = cA;
    if (last){
      const size_t ob = (size_t)T_SEQ * 128;
      stf(outBase, ob + 128 + d, cA, fo);
    }
  }
}

// ---------------- K3: logits[t][v] = hb[t] @ Wfc^T + bfc ----------------
__global__ __launch_bounds__(256) void k_fc(const u16* __restrict__ hb,
                                            const void* __restrict__ Wfc, const void* __restrict__ bfc,
                                            const int* __restrict__ flags,
                                            void* __restrict__ out, int t0){
  __shared__ __align__(16) float sh[32 * 128];
  const int fw = flags[13], fb = flags[14], fo = flags[0];
  const int tid = threadIdx.x;
  const int tl0 = blockIdx.x * 32;
  for (int i = tid; i < 32 * 128; i += 256) sh[i] = bf2f(hb[(size_t)tl0 * 128 + i]);
  __syncthreads();
  const int v  = tid & 127;
  const int tt = tid >> 7; // 0..1
  float bias = ldf(bfc, v, fb);
  float acc[16];
#pragma unroll
  for (int j = 0; j < 16; ++j) acc[j] = bias;
  if (!fw){
    const u32* wrow = (const u32*)Wfc + v * 64;
    for (int c = 0; c < 32; ++c){
      uint2 wp = *(const uint2*)(wrow + 2 * c);
      float w0 = bflo(wp.x), w1 = bfhi(wp.x), w2 = bflo(wp.y), w3 = bfhi(wp.y);
#pragma unroll
      for (int j = 0; j < 16; ++j){
        const f32x4 xv = *(const f32x4*)&sh[(tt + 2 * j) * 128 + 4 * c];
        acc[j] += w0 * xv.x + w1 * xv.y + w2 * xv.z + w3 * xv.w;
      }
    }
  } else {
    const float* wrow = (const float*)Wfc + v * 128;
    for (int c = 0; c < 32; ++c){
      const f32x4 wv = *(const f32x4*)(wrow + 4 * c);
#pragma unroll
      for (int j = 0; j < 16; ++j){
        const f32x4 xv = *(const f32x4*)&sh[(tt + 2 * j) * 128 + 4 * c];
        acc[j] += wv.x * xv.x + wv.y * xv.y + wv.z * xv.z + wv.w * xv.w;
      }
    }
  }
  for (int j = 0; j < 16; ++j)
    stf(out, (size_t)(t0 + tl0 + tt + 2 * j) * 128 + v, acc[j], fo);
}

extern "C" void kernel_launch(void* const* d_in, const int* in_sizes, int n_in,
                              void* d_out, int out_size, void* d_ws, size_t ws_size,
                              hipStream_t stream) {
  // ---- ws layout ----
  // [0,1024)      stF (cA,cB f32)
  // [1024,1536)   stH (hA,hB bf16)
  // [1536,1600)   flags (int[16])
  // [4096, +CHUNK*1024)           preA bf16 [CHUNK][512]
  // [4096+CHUNK*1024, +CHUNK*256) hb   bf16 [CHUNK][128]
  int CHUNK = 32;
  for (int c = T_SEQ; c >= 32; c >>= 1){
    size_t need = 4096 + (size_t)c * 1024 + (size_t)c * 256;
    if (need <= ws_size){ CHUNK = c; break; }
  }
  float* stF   = (float*)d_ws;
  u16*   stH   = (u16*)((char*)d_ws + 1024);
  int*   flags = (int*)((char*)d_ws + 1536);
  u16*   preA  = (u16*)((char*)d_ws + 4096);
  u16*   hb    = (u16*)((char*)d_ws + 4096 + (size_t)CHUNK * 1024);

  Ptrs ptrs;
  for (int i = 0; i < 15; ++i){ ptrs.p[i] = d_in[i]; ptrs.n[i] = in_sizes[i]; }
  k_detect<<<1, 64, 0, stream>>>(ptrs, flags);

  const int nChunks = T_SEQ / CHUNK;
  for (int c = 0; c < nChunks; ++c){
    const int t0 = c * CHUNK;
    k_pre <<<CHUNK / 32, 512, 0, stream>>>(d_in[0], d_in[5], d_in[6], d_in[8], flags, preA, t0);
    k_lstm<<<1,          512, 0, stream>>>(preA, d_in[1], d_in[2], d_in[3], d_in[4],
                                           d_in[7], d_in[9], d_in[11], d_in[10], d_in[12],
                                           flags, stF, stH, hb, d_out, t0, CHUNK);
    k_fc  <<<CHUNK / 32, 256, 0, stream>>>(hb, d_in[13], d_in[14], flags, d_out, t0);
  }
}

// Round 5
// 97746.344 us; speedup vs baseline: 1.1438x; 1.0481x over previous
//
#include <hip/hip_runtime.h>

typedef unsigned short u16;
typedef unsigned int   u32;
typedef __bf16 bf16x8 __attribute__((ext_vector_type(8)));
typedef float  f32x4  __attribute__((ext_vector_type(4)));

#define T_SEQ 65536

__device__ __forceinline__ float bf2f(u16 v){ return __uint_as_float(((u32)v) << 16); }
__device__ __forceinline__ float bflo(u32 w){ return __uint_as_float(w << 16); }
__device__ __forceinline__ float bfhi(u32 w){ return __uint_as_float(w & 0xFFFF0000u); }
__device__ __forceinline__ u16 f2bf(float f){
  u32 u = __float_as_uint(f);
  u32 r = (u + 0x7FFFu + ((u >> 16) & 1u)) >> 16;
  return (u16)r;
}
__device__ __forceinline__ float sigm(float x){ return 1.0f / (1.0f + __expf(-x)); }
__device__ __forceinline__ float tanh_(float x){ return 1.0f - 2.0f / (1.0f + __expf(2.0f * x)); }

// dtype-flagged boundary access: f==1 -> float32, f==0 -> bf16
__device__ __forceinline__ float ldf(const void* p, size_t i, int f){
  return f ? ((const float*)p)[i] : bf2f(((const u16*)p)[i]);
}
__device__ __forceinline__ void stf(void* p, size_t i, float v, int f){
  if (f) ((float*)p)[i] = v; else ((u16*)p)[i] = f2bf(v);
}

__device__ __forceinline__ bf16x8 ldg_frag(const u16* p){
  uint4 v = *(const uint4*)p;
  return __builtin_bit_cast(bf16x8, v);
}
__device__ __forceinline__ bf16x8 load_frag_dyn(const void* p, int off, int f){
  if (!f) return ldg_frag((const u16*)p + off);
  union { u16 h[8]; bf16x8 v; } t;
  const float* q = (const float*)p + off;
#pragma unroll
  for (int j = 0; j < 8; ++j) t.h[j] = f2bf(q[j]);
  return t.v;
}
__device__ __forceinline__ bf16x8 lds_frag(const u16* p){
  uint4 v = *(const uint4*)p;
  return __builtin_bit_cast(bf16x8, v);
}

// ---------------- K0: per-array dtype detector ----------------
struct Ptrs { const void* p[15]; int n[15]; };

__global__ void k_detect(Ptrs ptrs, int* flags){
  const int i = threadIdx.x;
  if (i >= 15) return;
  const u32* w = (const u32*)ptrs.p[i];
  int words = ptrs.n[i] >> 1; if (words > 256) words = 256;
  int bad = 0, good = 0;
  for (int j = 0; j < words; ++j){
    u32 lo = w[j] & 0xFFFFu;
    if (lo == 0) continue;
    u32 e = (lo >> 7) & 0xFFu;
    if (e >= 96 && e <= 135) ++good; else ++bad;
  }
  flags[i] = (bad > good) ? 1 : 0;
}

// ---------------- K1: out[t][r] = in[t] @ W^T + b1 + b2  (bf16 out, chunk-local rows) ----------------
// in: [.][128] (global rows offset tbase), fiIn<0 means fixed bf16; W: [512][128]
__global__ __launch_bounds__(512) void k_gemm(const void* __restrict__ in, const void* __restrict__ W,
                                              const void* __restrict__ b1, const void* __restrict__ b2,
                                              const int* __restrict__ flags,
                                              int fiIn, int fiW, int fiB1, int fiB2,
                                              u16* __restrict__ out, int tbase){
  __shared__ __align__(16) float sx[32 * 128];
  const int fin = (fiIn < 0) ? 0 : flags[fiIn];
  const int fw = flags[fiW], f1 = flags[fiB1], f2 = flags[fiB2];
  const int tid = threadIdx.x;
  const int tl0 = blockIdx.x * 32;
  const int tg0 = tbase + tl0;
  for (int i = tid; i < 32 * 128; i += 512) sx[i] = ldf(in, (size_t)tg0 * 128 + i, fin);
  __syncthreads();
  const int r = tid; // 0..511
  float bias = ldf(b1, r, f1) + ldf(b2, r, f2);
  float acc[32];
#pragma unroll
  for (int t = 0; t < 32; ++t) acc[t] = bias;
  if (!fw){
    const u32* wrow = (const u32*)W + r * 64;
    for (int c = 0; c < 32; ++c){
      uint2 wp = *(const uint2*)(wrow + 2 * c);
      float w0 = bflo(wp.x), w1 = bfhi(wp.x), w2 = bflo(wp.y), w3 = bfhi(wp.y);
#pragma unroll
      for (int t = 0; t < 32; ++t){
        const f32x4 xv = *(const f32x4*)&sx[t * 128 + 4 * c];
        acc[t] += w0 * xv.x + w1 * xv.y + w2 * xv.z + w3 * xv.w;
      }
    }
  } else {
    const float* wrow = (const float*)W + r * 128;
    for (int c = 0; c < 32; ++c){
      const f32x4 wv = *(const f32x4*)(wrow + 4 * c);
#pragma unroll
      for (int t = 0; t < 32; ++t){
        const f32x4 xv = *(const f32x4*)&sx[t * 128 + 4 * c];
        acc[t] += wv.x * xv.x + wv.y * xv.y + wv.z * xv.z + wv.w * xv.w;
      }
    }
  }
  for (int t = 0; t < 32; ++t) out[(size_t)(tl0 + t) * 512 + r] = f2bf(acc[t]);
}

// ---------------- K2: single-recurrence sequential LSTM half-cell ----------------
// Per step: g(t) = W @ h(t-1)  [MFMA, 16 instr/wave];  cell: h(t) = o*tanh(c), c = f*c + i*g
// pre[t] already contains the input-side contribution INCLUDING both biases.
// Only ONE weight matrix resident: 16 frags = 64 VGPR/wave -> no spills.
__global__ __launch_bounds__(512, 2) void k_rec(
    const u16* __restrict__ pre,              // [L][512] bf16 chunk-local
    const void* __restrict__ W,               // [512][128]
    const void* __restrict__ h0, const void* __restrict__ c0,
    const int* __restrict__ flags, int fiW, int fiH0, int fiC0,
    u16* __restrict__ stH, float* __restrict__ stC,   // persistent state (128 each)
    u16* __restrict__ hdump,                  // [L][128] bf16 chunk-local
    void* __restrict__ outBase, size_t outHoff, size_t outCoff,
    int first, int last, int L)
{
  __shared__ __align__(16) u16   sPre[2][16 * 512]; // 32 KB double-buffered pre chunks
  __shared__ __align__(16) u16   sHd[16 * 128];     // 4 KB h dump buffer
  __shared__ __align__(16) float sG[512];           // recurrent gates
  __shared__ __align__(16) u16   sH[128];           // current h (bf16)

  const int tid = threadIdx.x;
  const int w = tid >> 6;
  const int l = tid & 63;
  const int q = l >> 4;
  const int m = l & 15;
  const int fW = flags[fiW];
  const int fo = flags[0];

  // Resident weight fragments: wave w owns rows w*64..w*64+63 (4 row-tiles of 16)
  // A-frag layout (mfma_f32_16x16x32_bf16): A[m=lane&15][k=(lane>>4)*8+j]
  bf16x8 wf[4][4];
#pragma unroll
  for (int rt = 0; rt < 4; ++rt){
    const int row = (w * 4 + rt) * 16 + m;
#pragma unroll
    for (int kt = 0; kt < 4; ++kt)
      wf[rt][kt] = load_frag_dyn(W, row * 128 + kt * 32 + q * 8, fW);
  }

  float c = 0.f;
  if (tid < 128){
    if (first){
      c = ldf(c0, tid, flags[fiC0]);
      sH[tid] = f2bf(ldf(h0, tid, flags[fiH0]));
    } else {
      c = stC[tid];
      sH[tid] = stH[tid];
    }
  }
  // stage chunk 0 (16 KB = 1024 uint4)
  {
    const uint4* src = (const uint4*)pre;
    uint4* dst = (uint4*)&sPre[0][0];
    dst[tid]       = src[tid];
    dst[tid + 512] = src[tid + 512];
  }
  __syncthreads();

  for (int t = 0; t < L; ++t){
    const int slot = t & 15;
    const int buf  = (t >> 4) & 1;

    // ---- slot==0: issue next-chunk staging loads + flush previous 16 h rows ----
    uint4 st0, st1;
    bool doStage = false;
    int nc = 0;
    if (slot == 0){
      nc = (t >> 4) + 1;
      if (nc < (L >> 4)){
        doStage = true;
        const uint4* src = (const uint4*)pre;
        st0 = src[(size_t)nc * 1024 + tid];
        st1 = src[(size_t)nc * 1024 + 512 + tid];
      }
      if (t > 0 && tid < 256){
        const uint4* s = (const uint4*)sHd;
        ((uint4*)hdump)[(size_t)(t - 16) * 16 + tid] = s[tid];
      }
    }

    // ---- cell pre-gate preload (latency hidden under MFMA phase) ----
    float pp0, pp1, pp2, pp3;
    if (tid < 128){
      const u16* pc = &sPre[buf][slot * 512];
      pp0 = bf2f(pc[tid]);
      pp1 = bf2f(pc[128 + tid]);
      pp2 = bf2f(pc[256 + tid]);
      pp3 = bf2f(pc[384 + tid]);
    }

    // ---- MFMA phase: g(t) = W @ h(t-1) ----
    bf16x8 bh[4];
#pragma unroll
    for (int kt = 0; kt < 4; ++kt) bh[kt] = lds_frag(&sH[kt * 32 + q * 8]);
    f32x4 g[4];
#pragma unroll
    for (int rt = 0; rt < 4; ++rt) g[rt] = (f32x4){0.f, 0.f, 0.f, 0.f};
#pragma unroll
    for (int kt = 0; kt < 4; ++kt){
#pragma unroll
      for (int rt = 0; rt < 4; ++rt)
        g[rt] = __builtin_amdgcn_mfma_f32_16x16x32_bf16(wf[rt][kt], bh[kt], g[rt], 0, 0, 0);
    }
    if (m == 0){ // C/D col 0: lane 16q holds rows q*4+reg
#pragma unroll
      for (int rt = 0; rt < 4; ++rt)
        *(f32x4*)&sG[(w * 4 + rt) * 16 + q * 4] = g[rt];
    }
    if (doStage){
      uint4* dst = (uint4*)&sPre[nc & 1][0];
      dst[tid]       = st0;
      dst[tid + 512] = st1;
    }
    __syncthreads();

    // ---- cell phase ----
    if (tid < 128){
      float gi = sigm (pp0 + sG[tid]);
      float gf = sigm (pp1 + sG[128 + tid]);
      float gg = tanh_(pp2 + sG[256 + tid]);
      float go = sigm (pp3 + sG[384 + tid]);
      c = gf * c + gi * gg;
      u16 hq = f2bf(go * tanh_(c));
      sH[tid] = hq;
      sHd[slot * 128 + tid] = hq;
    }
    __syncthreads();
  }

  // epilogue: flush last 16 h rows + persist state
  if (tid < 256){
    const uint4* s = (const uint4*)sHd;
    ((uint4*)hdump)[(size_t)(L - 16) * 16 + tid] = s[tid];
  }
  if (tid < 128){
    stC[tid] = c;
    stH[tid] = sH[tid];
    if (last){
      stf(outBase, outHoff + tid, bf2f(sH[tid]), fo);
      stf(outBase, outCoff + tid, c,             fo);
    }
  }
}

// ---------------- K3: logits[t][v] = hb[t] @ Wfc^T + bfc ----------------
__global__ __launch_bounds__(256) void k_fc(const u16* __restrict__ hb,
                                            const void* __restrict__ Wfc, const void* __restrict__ bfc,
                                            const int* __restrict__ flags,
                                            void* __restrict__ out, int t0){
  __shared__ __align__(16) float sh[32 * 128];
  const int fw = flags[13], fb = flags[14], fo = flags[0];
  const int tid = threadIdx.x;
  const int tl0 = blockIdx.x * 32;
  for (int i = tid; i < 32 * 128; i += 256) sh[i] = bf2f(hb[(size_t)tl0 * 128 + i]);
  __syncthreads();
  const int v  = tid & 127;
  const int tt = tid >> 7; // 0..1
  float bias = ldf(bfc, v, fb);
  float acc[16];
#pragma unroll
  for (int j = 0; j < 16; ++j) acc[j] = bias;
  if (!fw){
    const u32* wrow = (const u32*)Wfc + v * 64;
    for (int c = 0; c < 32; ++c){
      uint2 wp = *(const uint2*)(wrow + 2 * c);
      float w0 = bflo(wp.x), w1 = bfhi(wp.x), w2 = bflo(wp.y), w3 = bfhi(wp.y);
#pragma unroll
      for (int j = 0; j < 16; ++j){
        const f32x4 xv = *(const f32x4*)&sh[(tt + 2 * j) * 128 + 4 * c];
        acc[j] += w0 * xv.x + w1 * xv.y + w2 * xv.z + w3 * xv.w;
      }
    }
  } else {
    const float* wrow = (const float*)Wfc + v * 128;
    for (int c = 0; c < 32; ++c){
      const f32x4 wv = *(const f32x4*)(wrow + 4 * c);
#pragma unroll
      for (int j = 0; j < 16; ++j){
        const f32x4 xv = *(const f32x4*)&sh[(tt + 2 * j) * 128 + 4 * c];
        acc[j] += wv.x * xv.x + wv.y * xv.y + wv.z * xv.z + wv.w * xv.w;
      }
    }
  }
  for (int j = 0; j < 16; ++j)
    stf(out, (size_t)(t0 + tl0 + tt + 2 * j) * 128 + v, acc[j], fo);
}

extern "C" void kernel_launch(void* const* d_in, const int* in_sizes, int n_in,
                              void* d_out, int out_size, void* d_ws, size_t ws_size,
                              hipStream_t stream) {
  // ---- ws layout ----
  // [0,512)       stC_A (f32 x128), [512,1024) stC_B
  // [1024,1280)   stH_A (bf16 x128), [1280,1536) stH_B
  // [1536,1600)   flags (int[16])
  // [4096, +CHUNK*1024)   preA bf16 [CHUNK][512]
  // next CHUNK*1024       preB bf16 [CHUNK][512]
  // next CHUNK*256        hA_ws bf16 [CHUNK][128]
  // next CHUNK*256        hb    bf16 [CHUNK][128]
  int CHUNK = 32;
  for (int c = T_SEQ; c >= 32; c >>= 1){
    size_t need = 4096 + (size_t)c * 2560;
    if (need <= ws_size){ CHUNK = c; break; }
  }
  float* stC_A = (float*)d_ws;
  float* stC_B = (float*)((char*)d_ws + 512);
  u16*   stH_A = (u16*)((char*)d_ws + 1024);
  u16*   stH_B = (u16*)((char*)d_ws + 1280);
  int*   flags = (int*)((char*)d_ws + 1536);
  u16*   preA  = (u16*)((char*)d_ws + 4096);
  u16*   preB  = (u16*)((char*)d_ws + 4096 + (size_t)CHUNK * 1024);
  u16*   hA_ws = (u16*)((char*)d_ws + 4096 + (size_t)CHUNK * 2048);
  u16*   hb    = (u16*)((char*)d_ws + 4096 + (size_t)CHUNK * 2048 + (size_t)CHUNK * 256);

  Ptrs ptrs;
  for (int i = 0; i < 15; ++i){ ptrs.p[i] = d_in[i]; ptrs.n[i] = in_sizes[i]; }
  k_detect<<<1, 64, 0, stream>>>(ptrs, flags);

  const size_t obase = (size_t)T_SEQ * 128;
  const int nChunks = T_SEQ / CHUNK;
  for (int c = 0; c < nChunks; ++c){
    const int t0 = c * CHUNK;
    const int first = (c == 0), last = (c == nChunks - 1);
    // preA = x @ WA1^T + bA1 + bA2
    k_gemm<<<CHUNK / 32, 512, 0, stream>>>(d_in[0], d_in[5], d_in[6], d_in[8], flags,
                                           0, 5, 6, 8, preA, t0);
    // pass A: hA recurrence (WA2 resident)
    k_rec <<<1, 512, 0, stream>>>(preA, d_in[7], d_in[1], d_in[2], flags, 7, 1, 2,
                                  stH_A, stC_A, hA_ws, d_out, obase, obase + 128,
                                  first, last, CHUNK);
    // preB = hA @ WB1^T + bB1 + bB2
    k_gemm<<<CHUNK / 32, 512, 0, stream>>>(hA_ws, d_in[9], d_in[10], d_in[12], flags,
                                           -1, 9, 10, 12, preB, 0);
    // pass B: hB recurrence (WB2 resident)
    k_rec <<<1, 512, 0, stream>>>(preB, d_in[11], d_in[3], d_in[4], flags, 11, 3, 4,
                                  stH_B, stC_B, hb, d_out, obase + 256, obase + 384,
                                  first, last, CHUNK);
    // logits
    k_fc  <<<CHUNK / 32, 256, 0, stream>>>(hb, d_in[13], d_in[14], flags, d_out, t0);
  }
}

// Round 6
// 57404.340 us; speedup vs baseline: 1.9476x; 1.7028x over previous
//
#include <hip/hip_runtime.h>

typedef unsigned short u16;
typedef unsigned int   u32;
typedef __bf16 bf16x8 __attribute__((ext_vector_type(8)));
typedef float  f32x4  __attribute__((ext_vector_type(4)));

#define T_SEQ 65536

__device__ __forceinline__ float bf2f(u16 v){ return __uint_as_float(((u32)v) << 16); }
__device__ __forceinline__ float bflo(u32 w){ return __uint_as_float(w << 16); }
__device__ __forceinline__ float bfhi(u32 w){ return __uint_as_float(w & 0xFFFF0000u); }
__device__ __forceinline__ u16 f2bf(float f){
  u32 u = __float_as_uint(f);
  u32 r = (u + 0x7FFFu + ((u >> 16) & 1u)) >> 16;
  return (u16)r;
}
__device__ __forceinline__ float sigm(float x){ return 1.0f / (1.0f + __expf(-x)); }
__device__ __forceinline__ float tanh_(float x){ return 1.0f - 2.0f / (1.0f + __expf(2.0f * x)); }

__device__ __forceinline__ float ldf(const void* p, size_t i, int f){
  return f ? ((const float*)p)[i] : bf2f(((const u16*)p)[i]);
}
__device__ __forceinline__ void stf(void* p, size_t i, float v, int f){
  if (f) ((float*)p)[i] = v; else ((u16*)p)[i] = f2bf(v);
}

__device__ __forceinline__ bf16x8 ldg_frag(const u16* p){
  uint4 v = *(const uint4*)p;
  return __builtin_bit_cast(bf16x8, v);
}
__device__ __forceinline__ bf16x8 load_frag_dyn(const void* p, int off, int f){
  if (!f) return ldg_frag((const u16*)p + off);
  union { u16 h[8]; bf16x8 v; } t;
  const float* q = (const float*)p + off;
#pragma unroll
  for (int j = 0; j < 8; ++j) t.h[j] = f2bf(q[j]);
  return t.v;
}
__device__ __forceinline__ bf16x8 lds_frag(const u16* p){
  uint4 v = *(const uint4*)p;
  return __builtin_bit_cast(bf16x8, v);
}

// ---------------- K0: per-array dtype detector ----------------
struct Ptrs { const void* p[15]; int n[15]; };

__global__ void k_detect(Ptrs ptrs, int* flags){
  const int i = threadIdx.x;
  if (i >= 15) return;
  const u32* w = (const u32*)ptrs.p[i];
  int words = ptrs.n[i] >> 1; if (words > 256) words = 256;
  int bad = 0, good = 0;
  for (int j = 0; j < words; ++j){
    u32 lo = w[j] & 0xFFFFu;
    if (lo == 0) continue;
    u32 e = (lo >> 7) & 0xFFu;
    if (e >= 96 && e <= 135) ++good; else ++bad;
  }
  flags[i] = (bad > good) ? 1 : 0;
}

// ---------------- K1: preA[t][r] = x[t] @ WA1^T + bA1 + bA2 ----------------
__global__ __launch_bounds__(512) void k_gemm(const void* __restrict__ in, const void* __restrict__ W,
                                              const void* __restrict__ b1, const void* __restrict__ b2,
                                              const int* __restrict__ flags,
                                              int fiIn, int fiW, int fiB1, int fiB2,
                                              u16* __restrict__ out, int tbase){
  __shared__ __align__(16) float sx[32 * 128];
  const int fin = (fiIn < 0) ? 0 : flags[fiIn];
  const int fw = flags[fiW], f1 = flags[fiB1], f2 = flags[fiB2];
  const int tid = threadIdx.x;
  const int tl0 = blockIdx.x * 32;
  const int tg0 = tbase + tl0;
  for (int i = tid; i < 32 * 128; i += 512) sx[i] = ldf(in, (size_t)tg0 * 128 + i, fin);
  __syncthreads();
  const int r = tid;
  float bias = ldf(b1, r, f1) + ldf(b2, r, f2);
  float acc[32];
#pragma unroll
  for (int t = 0; t < 32; ++t) acc[t] = bias;
  if (!fw){
    const u32* wrow = (const u32*)W + r * 64;
    for (int c = 0; c < 32; ++c){
      uint2 wp = *(const uint2*)(wrow + 2 * c);
      float w0 = bflo(wp.x), w1 = bfhi(wp.x), w2 = bflo(wp.y), w3 = bfhi(wp.y);
#pragma unroll
      for (int t = 0; t < 32; ++t){
        const f32x4 xv = *(const f32x4*)&sx[t * 128 + 4 * c];
        acc[t] += w0 * xv.x + w1 * xv.y + w2 * xv.z + w3 * xv.w;
      }
    }
  } else {
    const float* wrow = (const float*)W + r * 128;
    for (int c = 0; c < 32; ++c){
      const f32x4 wv = *(const f32x4*)(wrow + 4 * c);
#pragma unroll
      for (int t = 0; t < 32; ++t){
        const f32x4 xv = *(const f32x4*)&sx[t * 128 + 4 * c];
        acc[t] += wv.x * xv.x + wv.y * xv.y + wv.z * xv.z + wv.w * xv.w;
      }
    }
  }
  for (int t = 0; t < 32; ++t) out[(size_t)(tl0 + t) * 512 + r] = f2bf(acc[t]);
}

// ---------------- K2: 3-block pipelined dual recurrence ----------------
// Block 0: rec A (WA2). Publishes hA groups (16 steps) -> flagA[g].
// Block 1: preB[t] = WB1 @ hA(t) + bB1 + bB2, batched 16 timesteps/group (16 real
//          B-columns -> full MFMA efficiency). Waits flagA[g], publishes flagP[g].
// Block 2: rec B (WB2). Waits flagP[g], consumes preB groups, dumps hb.
__global__ __launch_bounds__(512, 2) void k_dual(
    const u16* __restrict__ preA, u16* __restrict__ preB,
    u16* __restrict__ hAws, u16* __restrict__ hb,
    const void* __restrict__ WA2, const void* __restrict__ WB1, const void* __restrict__ WB2,
    const void* __restrict__ hA0, const void* __restrict__ cA0,
    const void* __restrict__ hB0, const void* __restrict__ cB0,
    const void* __restrict__ bB1, const void* __restrict__ bB2,
    const int* __restrict__ flags, u32* __restrict__ flagA, u32* __restrict__ flagP,
    u16* __restrict__ stH, float* __restrict__ stC,
    void* __restrict__ outBase, int first, int last, int L)
{
  __shared__ __align__(16) u16   sPre[2][16 * 512]; // 32 KB
  __shared__ __align__(16) u16   sHd[16 * 128];     // 4 KB
  __shared__ __align__(16) float sG[512];
  __shared__ __align__(16) u16   sH[128];

  const int tid = threadIdx.x;
  const int w = tid >> 6, l = tid & 63, q = l >> 4, m = l & 15;
  const int fo = flags[0];
  const int role = blockIdx.x;
  const int G = L >> 4;

  if (role == 1){
    // ---------- preB producer ----------
    const int fW = flags[9], f1 = flags[10], f2 = flags[12];
    bf16x8 wf[4][4];
#pragma unroll
    for (int rt = 0; rt < 4; ++rt){
      const int row = (w * 4 + rt) * 16 + m;
#pragma unroll
      for (int kt = 0; kt < 4; ++kt)
        wf[rt][kt] = load_frag_dyn(WB1, row * 128 + kt * 32 + q * 8, fW);
    }
    float bias[4][4];
#pragma unroll
    for (int rt = 0; rt < 4; ++rt)
#pragma unroll
      for (int rg = 0; rg < 4; ++rg){
        const int r = (w * 4 + rt) * 16 + q * 4 + rg;
        bias[rt][rg] = ldf(bB1, r, f1) + ldf(bB2, r, f2);
      }
    for (int g = 0; g < G; ++g){
      if (tid == 0){
        while (atomicAdd(&flagA[g], 0u) == 0u) __builtin_amdgcn_s_sleep(8);
      }
      __syncthreads();
      const u16* hg = hAws + (size_t)g * 2048; // 16 rows x 128
      f32x4 acc[4];
#pragma unroll
      for (int rt = 0; rt < 4; ++rt) acc[rt] = (f32x4){0.f, 0.f, 0.f, 0.f};
#pragma unroll
      for (int kt = 0; kt < 4; ++kt){
        bf16x8 bfrag = ldg_frag(hg + m * 128 + kt * 32 + q * 8); // col m = timestep
#pragma unroll
        for (int rt = 0; rt < 4; ++rt)
          acc[rt] = __builtin_amdgcn_mfma_f32_16x16x32_bf16(wf[rt][kt], bfrag, acc[rt], 0, 0, 0);
      }
      const int tg = g * 16 + m;
#pragma unroll
      for (int rt = 0; rt < 4; ++rt){
        ushort4 o;
        o.x = f2bf(acc[rt].x + bias[rt][0]);
        o.y = f2bf(acc[rt].y + bias[rt][1]);
        o.z = f2bf(acc[rt].z + bias[rt][2]);
        o.w = f2bf(acc[rt].w + bias[rt][3]);
        *(ushort4*)(preB + (size_t)tg * 512 + (w * 4 + rt) * 16 + q * 4) = o;
      }
      __threadfence();
      __syncthreads();
      if (tid == 0) atomicExch(&flagP[g], 1u);
    }
    return;
  }

  // ---------- roles 0 / 2: recurrence ----------
  const bool isA = (role == 0);
  const u16* pre = isA ? preA : preB;
  u16* hdump = isA ? hAws : hb;
  const void* Wm = isA ? WA2 : WB2;
  const void* h0 = isA ? hA0 : hB0;
  const void* c0 = isA ? cA0 : cB0;
  const int fW  = isA ? flags[7] : flags[11];
  const int fH0 = isA ? flags[1] : flags[3];
  const int fC0 = isA ? flags[2] : flags[4];
  const int sto = isA ? 0 : 128;

  bf16x8 wf[4][4];
#pragma unroll
  for (int rt = 0; rt < 4; ++rt){
    const int row = (w * 4 + rt) * 16 + m;
#pragma unroll
    for (int kt = 0; kt < 4; ++kt)
      wf[rt][kt] = load_frag_dyn(Wm, row * 128 + kt * 32 + q * 8, fW);
  }

  float c = 0.f;
  if (tid < 128){
    if (first){
      c = ldf(c0, tid, fC0);
      sH[tid] = f2bf(ldf(h0, tid, fH0));
    } else {
      c = stC[sto + tid];
      sH[tid] = stH[sto + tid];
    }
  }
  if (isA){
    const uint4* src = (const uint4*)pre;
    uint4* dst = (uint4*)&sPre[0][0];
    dst[tid]       = src[tid];
    dst[tid + 512] = src[tid + 512];
  }
  __syncthreads();

  for (int t = 0; t < L; ++t){
    const int slot = t & 15;
    const int buf  = isA ? ((t >> 4) & 1) : 0;

    uint4 st0, st1;
    bool doStage = false;
    int nc = 0;
    if (slot == 0){
      if (isA){
        // flush previous hA group, fence, then prefetch next preA group
        if (t > 0 && tid < 256){
          const uint4* s = (const uint4*)sHd;
          ((uint4*)hdump)[(size_t)(t - 16) * 16 + tid] = s[tid];
          __threadfence();
        }
        nc = (t >> 4) + 1;
        if (nc < G){
          doStage = true;
          const uint4* src = (const uint4*)pre;
          st0 = src[(size_t)nc * 1024 + tid];
          st1 = src[(size_t)nc * 1024 + 512 + tid];
        }
      } else {
        // wait for preB group, load into sPre[0], flush previous hb group
        const int g = t >> 4;
        if (tid == 0){
          while (atomicAdd(&flagP[g], 0u) == 0u) __builtin_amdgcn_s_sleep(8);
        }
        __syncthreads();
        const uint4* src = (const uint4*)(pre + (size_t)g * 8192);
        uint4* dst = (uint4*)&sPre[0][0];
        dst[tid]       = src[tid];
        dst[tid + 512] = src[tid + 512];
        if (t > 0 && tid < 256){
          const uint4* s = (const uint4*)sHd;
          ((uint4*)hdump)[(size_t)(t - 16) * 16 + tid] = s[tid];
        }
        __syncthreads(); // LDS group visible before pp preload
      }
    }

    // cell pre-gate preload (hidden under MFMA)
    float pp0, pp1, pp2, pp3;
    if (tid < 128){
      const u16* pc = &sPre[buf][slot * 512];
      pp0 = bf2f(pc[tid]);
      pp1 = bf2f(pc[128 + tid]);
      pp2 = bf2f(pc[256 + tid]);
      pp3 = bf2f(pc[384 + tid]);
    }

    // MFMA: g(t) = W @ h(t-1)
    bf16x8 bh[4];
#pragma unroll
    for (int kt = 0; kt < 4; ++kt) bh[kt] = lds_frag(&sH[kt * 32 + q * 8]);
    f32x4 g[4];
#pragma unroll
    for (int rt = 0; rt < 4; ++rt) g[rt] = (f32x4){0.f, 0.f, 0.f, 0.f};
#pragma unroll
    for (int kt = 0; kt < 4; ++kt){
#pragma unroll
      for (int rt = 0; rt < 4; ++rt)
        g[rt] = __builtin_amdgcn_mfma_f32_16x16x32_bf16(wf[rt][kt], bh[kt], g[rt], 0, 0, 0);
    }
    if (m == 0){
#pragma unroll
      for (int rt = 0; rt < 4; ++rt)
        *(f32x4*)&sG[(w * 4 + rt) * 16 + q * 4] = g[rt];
    }
    if (doStage){
      uint4* dst = (uint4*)&sPre[nc & 1][0];
      dst[tid]       = st0;
      dst[tid + 512] = st1;
    }
    __syncthreads();

    // publish previous hA group (block 0) after barrier
    if (isA && slot == 0 && t > 0 && tid == 448)
      atomicExch(&flagA[(t >> 4) - 1], 1u);

    // cell
    if (tid < 128){
      float gi = sigm (pp0 + sG[tid]);
      float gf = sigm (pp1 + sG[128 + tid]);
      float gg = tanh_(pp2 + sG[256 + tid]);
      float go = sigm (pp3 + sG[384 + tid]);
      c = gf * c + gi * gg;
      u16 hq = f2bf(go * tanh_(c));
      sH[tid] = hq;
      sHd[slot * 128 + tid] = hq;
    }
    __syncthreads();
  }

  // epilogue: flush last group, publish, persist state
  if (tid < 256){
    const uint4* s = (const uint4*)sHd;
    ((uint4*)hdump)[(size_t)(L - 16) * 16 + tid] = s[tid];
    __threadfence();
  }
  __syncthreads();
  if (isA && tid == 0) atomicExch(&flagA[G - 1], 1u);
  if (tid < 128){
    stC[sto + tid] = c;
    stH[sto + tid] = sH[tid];
    if (last){
      const size_t ob = (size_t)T_SEQ * 128;
      const size_t hOff = isA ? 0 : 256;
      const size_t cOff = isA ? 128 : 384;
      stf(outBase, ob + hOff + tid, bf2f(sH[tid]), fo);
      stf(outBase, ob + cOff + tid, c,             fo);
    }
  }
}

// ---------------- K3: logits[t][v] = hb[t] @ Wfc^T + bfc ----------------
__global__ __launch_bounds__(256) void k_fc(const u16* __restrict__ hb,
                                            const void* __restrict__ Wfc, const void* __restrict__ bfc,
                                            const int* __restrict__ flags,
                                            void* __restrict__ out, int t0){
  __shared__ __align__(16) float sh[32 * 128];
  const int fw = flags[13], fb = flags[14], fo = flags[0];
  const int tid = threadIdx.x;
  const int tl0 = blockIdx.x * 32;
  for (int i = tid; i < 32 * 128; i += 256) sh[i] = bf2f(hb[(size_t)tl0 * 128 + i]);
  __syncthreads();
  const int v  = tid & 127;
  const int tt = tid >> 7;
  float bias = ldf(bfc, v, fb);
  float acc[16];
#pragma unroll
  for (int j = 0; j < 16; ++j) acc[j] = bias;
  if (!fw){
    const u32* wrow = (const u32*)Wfc + v * 64;
    for (int c = 0; c < 32; ++c){
      uint2 wp = *(const uint2*)(wrow + 2 * c);
      float w0 = bflo(wp.x), w1 = bfhi(wp.x), w2 = bflo(wp.y), w3 = bfhi(wp.y);
#pragma unroll
      for (int j = 0; j < 16; ++j){
        const f32x4 xv = *(const f32x4*)&sh[(tt + 2 * j) * 128 + 4 * c];
        acc[j] += w0 * xv.x + w1 * xv.y + w2 * xv.z + w3 * xv.w;
      }
    }
  } else {
    const float* wrow = (const float*)Wfc + v * 128;
    for (int c = 0; c < 32; ++c){
      const f32x4 wv = *(const f32x4*)(wrow + 4 * c);
#pragma unroll
      for (int j = 0; j < 16; ++j){
        const f32x4 xv = *(const f32x4*)&sh[(tt + 2 * j) * 128 + 4 * c];
        acc[j] += wv.x * xv.x + wv.y * xv.y + wv.z * xv.z + wv.w * xv.w;
      }
    }
  }
  for (int j = 0; j < 16; ++j)
    stf(out, (size_t)(t0 + tl0 + tt + 2 * j) * 128 + v, acc[j], fo);
}

extern "C" void kernel_launch(void* const* d_in, const int* in_sizes, int n_in,
                              void* d_out, int out_size, void* d_ws, size_t ws_size,
                              hipStream_t stream) {
  // ---- ws layout ----
  // [0,1024)      stC  (f32: A at 0..127, B at 128..255)
  // [1024,1536)   stH  (bf16: A, B)
  // [1536,1600)   dtype flags (int[16])
  // [2048, +4G)   flagA ; [+4G, +8G) flagP      (G = CHUNK/16)
  // dataOff:      preA [CHUNK*1024] | preB [CHUNK*1024] | hAws [CHUNK*256] | hb [CHUNK*256]
  int CHUNK = 32;
  size_t dataOff = 4096;
  for (int c = T_SEQ; c >= 32; c >>= 1){
    size_t G = (size_t)c / 16;
    size_t dOff = (2048 + 8 * G + 4095) & ~(size_t)4095;
    size_t need = dOff + (size_t)c * 2560;
    if (need <= ws_size){ CHUNK = c; dataOff = dOff; break; }
  }
  const size_t G = (size_t)CHUNK / 16;
  float* stC    = (float*)d_ws;
  u16*   stH    = (u16*)((char*)d_ws + 1024);
  int*   dflags = (int*)((char*)d_ws + 1536);
  u32*   flagA  = (u32*)((char*)d_ws + 2048);
  u32*   flagP  = (u32*)((char*)d_ws + 2048 + 4 * G);
  u16*   preA   = (u16*)((char*)d_ws + dataOff);
  u16*   preB   = (u16*)((char*)d_ws + dataOff + (size_t)CHUNK * 1024);
  u16*   hAws   = (u16*)((char*)d_ws + dataOff + (size_t)CHUNK * 2048);
  u16*   hb     = (u16*)((char*)d_ws + dataOff + (size_t)CHUNK * 2048 + (size_t)CHUNK * 256);

  Ptrs ptrs;
  for (int i = 0; i < 15; ++i){ ptrs.p[i] = d_in[i]; ptrs.n[i] = in_sizes[i]; }
  k_detect<<<1, 64, 0, stream>>>(ptrs, dflags);

  const int nChunks = T_SEQ / CHUNK;
  for (int c = 0; c < nChunks; ++c){
    const int t0 = c * CHUNK;
    const int first = (c == 0), last = (c == nChunks - 1);
    hipMemsetAsync(flagA, 0, 8 * G, stream);
    k_gemm<<<CHUNK / 32, 512, 0, stream>>>(d_in[0], d_in[5], d_in[6], d_in[8], dflags,
                                           0, 5, 6, 8, preA, t0);
    k_dual<<<3, 512, 0, stream>>>(preA, preB, hAws, hb,
                                  d_in[7], d_in[9], d_in[11],
                                  d_in[1], d_in[2], d_in[3], d_in[4],
                                  d_in[10], d_in[12],
                                  dflags, flagA, flagP, stH, stC,
                                  d_out, first, last, CHUNK);
    k_fc  <<<CHUNK / 32, 256, 0, stream>>>(hb, d_in[13], d_in[14], dflags, d_out, t0);
  }
}